// Round 8
// baseline (574.653 us; speedup 1.0000x reference)
//
#include <hip/hip_runtime.h>

#define B_ 64
#define L_ 2048
#define G_ 512
#define F_ 3072
#define N_ 5632
#define NT_ 360448
#define EG_ 16384
#define E_ 1048576
#define EPS_ 1e-5f
#define MAXE_ 8192
#define CST_ 66      // cat tile stride in ushorts (33 dwords, odd -> ~2-way banks)

typedef __attribute__((ext_vector_type(8))) short bf8v;
typedef __attribute__((ext_vector_type(4))) float f4v;

__device__ __forceinline__ unsigned short f2bf(float f){
  unsigned int u=__float_as_uint(f);
  unsigned int r=(u + 0x7fffu + ((u>>16)&1u))>>16;
  return (unsigned short)r;
}
__device__ __forceinline__ float bf2f(unsigned short h){
  return __uint_as_float(((unsigned int)h)<<16);
}

// ---------------- fused init: cnt=0, mdT=0, ecnt=0, wcat build ----------------
__global__ void k_init(int* __restrict__ cnt, float* __restrict__ mdT, int* __restrict__ ecnt,
                       const float* __restrict__ wrel, const float* __restrict__ wroot,
                       unsigned short* __restrict__ wcat){
  int i=blockIdx.x*256+threadIdx.x;      // grid covers L_*64 = 131072
  if(i<L_*64) mdT[i]=0.f;
  if(i<N_) cnt[i]=0;
  if(i==0) *ecnt=0;
  if(i<32768){
    int l=i>>13; int rest=i&8191; int n=rest>>7; int k=rest&127;
    float v=(k<64)? wrel[((long)l*64+n)*64+k] : wroot[((long)l*64+n)*64+(k-64)];
    wcat[i]=f2bf(v);
  }
}

// ---------------- CSR build (shared topology = first EG edges, graph 0) ----------------
__global__ void k_hist(const int* __restrict__ ei, int* __restrict__ cnt){
  int e=blockIdx.x*256+threadIdx.x;
  if(e<EG_) atomicAdd(&cnt[ei[E_+e]],1);
}

// single block: shuffle scan over counts, then scatter packed (src | dst<<16) edges
__global__ void k_scan(const int* __restrict__ cnt, int* __restrict__ off, int* __restrict__ cur,
                       const int* __restrict__ ei, int* __restrict__ srcs){
  __shared__ int wsum[16];
  __shared__ int carry_s;
  int t=threadIdx.x, lane=t&63, wid=t>>6;
  if(t==0) carry_s=0;
  __syncthreads();
  for(int base=0;base<N_;base+=1024){
    int i=base+t;
    int v=(i<N_)?cnt[i]:0;
    int s=v;
    #pragma unroll
    for(int o=1;o<64;o<<=1){ int u=__shfl_up(s,o,64); if(lane>=o) s+=u; }
    if(lane==63) wsum[wid]=s;
    __syncthreads();
    if(t==0){
      int run=carry_s;
      #pragma unroll
      for(int q=0;q<16;q++){ int tmp=wsum[q]; wsum[q]=run; run+=tmp; }
      carry_s=run;
    }
    __syncthreads();
    int ex=wsum[wid]+s-v;
    if(i<N_){ off[i]=ex; cur[i]=ex; }
    __syncthreads();
  }
  if(t==0) off[N_]=carry_s;
  __syncthreads();
  for(int e=t;e<EG_;e+=1024){
    int d=ei[E_+e];
    int p=atomicAdd(&cur[d],1);
    srcs[p]=ei[e] | (d<<16);
  }
}

// ---------------- encoder + fused LN (produces hnA bf16 for layer 0) ----------------
__global__ __launch_bounds__(256) void k_enc(const float* __restrict__ x, unsigned short* __restrict__ hn,
    const float* __restrict__ ew, const float* __restrict__ eb,
    const float* __restrict__ lng, const float* __restrict__ lnb){
  int lane=threadIdx.x&63, wid=threadIdx.x>>6;
  int node0=blockIdx.x*32+wid*8;
  float w[7];
  #pragma unroll
  for(int k=0;k<7;k++) w[k]=ew[lane*7+k];
  float bias=eb[lane], gam=lng[lane], bet=lnb[lane];
  for(int t=0;t<8;t++){
    long n=node0+t;
    float acc=bias;
    #pragma unroll
    for(int k=0;k<7;k++) acc += x[n*7+k]*w[k];
    acc=fmaxf(acc,0.f);
    float s1=acc, s2=acc*acc;
    #pragma unroll
    for(int o=32;o>0;o>>=1){ s1+=__shfl_xor(s1,o,64); s2+=__shfl_xor(s2,o,64); }
    float mu=s1*(1.f/64.f);
    float var=s2*(1.f/64.f)-mu*mu;
    float inv=rsqrtf(var+EPS_);
    hn[n*64+lane]=f2bf((acc-mu)*inv*gam+bet);
  }
}

// ---------------- fused layer: scalar-fed gather -> MFMA -> epilogue (barrier-free) ----------------
// wave w owns dst nodes [w*16, w*16+16); lane = channel. Edge stream read via uniform
// (scalar-pipe) loads; edges sorted by dst -> running flush into this wave's cat rows.
__global__ __launch_bounds__(256,6) void k_layer(const unsigned short* __restrict__ hs,
    unsigned short* __restrict__ hd, const int* __restrict__ off, const int* __restrict__ srcs,
    const unsigned short* __restrict__ wcat, const float* __restrict__ brel,
    const float* __restrict__ lng, const float* __restrict__ lnb, int do_ln){
  __shared__ unsigned short cat[64*CST_];
  int tid=threadIdx.x;
  int w=tid>>6, lane=tid&63;
  int bid=blockIdx.x;
  const int P=N_/64;                 // 88 blocks per graph
  int r8=bid/(8*P), rem=bid%(8*P);
  int xcd=rem&7, jj=rem>>3, g=r8*8+xcd;   // one graph per XCD's L2
  int nodebase=jj*64;
  const unsigned short* hg = hs + (long)g*N_*64;
  int w16=w*16;

  // ---- phase 1: uniform edge stream + sorted-dst running flush ----
  {
    int kb=__builtin_amdgcn_readfirstlane(off[nodebase+w16]);
    int ke=__builtin_amdgcn_readfirstlane(off[nodebase+w16+16]);
    float acc=0.f;
    int dcur=w16;
#define FLUSH_(dd) while(dcur<(dd)){ cat[dcur*CST_+lane]=f2bf(acc); acc=0.f; dcur++; }
    int k=kb;
    for(; k+3<ke; k+=4){
      int u0=__builtin_amdgcn_readfirstlane(srcs[k]);
      int u1=__builtin_amdgcn_readfirstlane(srcs[k+1]);
      int u2=__builtin_amdgcn_readfirstlane(srcs[k+2]);
      int u3=__builtin_amdgcn_readfirstlane(srcs[k+3]);
      unsigned short a0=hg[(long)(u0&0xffff)*64+lane];
      unsigned short a1=hg[(long)(u1&0xffff)*64+lane];
      unsigned short a2=hg[(long)(u2&0xffff)*64+lane];
      unsigned short a3=hg[(long)(u3&0xffff)*64+lane];
      int d0=(u0>>16)-nodebase; FLUSH_(d0); acc+=bf2f(a0);
      int d1=(u1>>16)-nodebase; FLUSH_(d1); acc+=bf2f(a1);
      int d2=(u2>>16)-nodebase; FLUSH_(d2); acc+=bf2f(a2);
      int d3=(u3>>16)-nodebase; FLUSH_(d3); acc+=bf2f(a3);
    }
    for(; k<ke; k++){
      int u=__builtin_amdgcn_readfirstlane(srcs[k]);
      unsigned short a=hg[(long)(u&0xffff)*64+lane];
      int d=(u>>16)-nodebase; FLUSH_(d); acc+=bf2f(a);
    }
    FLUSH_(w16+16);
#undef FLUSH_
  }
  // no barrier: wave w writes and reads only cat rows [w16, w16+16)

  // ---- phase 2: MFMA [agg|root] @ Wcat^T, fused epilogue ----
  int m=lane&15, quad=lane>>4;
  int row=w16+m;
  const unsigned short* arow=&cat[row*CST_];
  bf8v af0=*(const bf8v*)(arow + quad*8);
  bf8v af1=*(const bf8v*)(arow + 32 + quad*8);
  const unsigned short* hrow=hg+(long)(nodebase+row)*64;
  bf8v af2=*(const bf8v*)(hrow+quad*8);
  bf8v af3=*(const bf8v*)(hrow+32+quad*8);
  f4v acc[4];
  float bias_nt[4], g_nt[4], b_nt[4];
  #pragma unroll
  for(int nt=0;nt<4;nt++){
    int c=nt*16+m;
    bias_nt[nt]=brel[c];
    g_nt[nt]=lng[c]; b_nt[nt]=lnb[c];
    acc[nt]=(f4v){0.f,0.f,0.f,0.f};
    const unsigned short* wrow=wcat + (long)c*128 + quad*8;
    bf8v b0=*(const bf8v*)(wrow);
    bf8v b1=*(const bf8v*)(wrow+32);
    bf8v b2=*(const bf8v*)(wrow+64);
    bf8v b3=*(const bf8v*)(wrow+96);
    acc[nt]=__builtin_amdgcn_mfma_f32_16x16x32_bf16(af0,b0,acc[nt],0,0,0);
    acc[nt]=__builtin_amdgcn_mfma_f32_16x16x32_bf16(af1,b1,acc[nt],0,0,0);
    acc[nt]=__builtin_amdgcn_mfma_f32_16x16x32_bf16(af2,b2,acc[nt],0,0,0);
    acc[nt]=__builtin_amdgcn_mfma_f32_16x16x32_bf16(af3,b3,acc[nt],0,0,0);
  }
  float v[4][4];
  #pragma unroll
  for(int nt=0;nt<4;nt++)
    #pragma unroll
    for(int r=0;r<4;r++)
      v[nt][r]=fmaxf(acc[nt][r]+bias_nt[nt],0.f);
  if(do_ln){
    #pragma unroll
    for(int r=0;r<4;r++){
      float rs=v[0][r]+v[1][r]+v[2][r]+v[3][r];
      float rss=v[0][r]*v[0][r]+v[1][r]*v[1][r]+v[2][r]*v[2][r]+v[3][r]*v[3][r];
      #pragma unroll
      for(int o=1;o<16;o<<=1){ rs+=__shfl_xor(rs,o,64); rss+=__shfl_xor(rss,o,64); }
      float mu=rs*(1.f/64.f);
      float var=rss*(1.f/64.f)-mu*mu;
      float inv=rsqrtf(var+EPS_);
      #pragma unroll
      for(int nt=0;nt<4;nt++) v[nt][r]=(v[nt][r]-mu)*inv*g_nt[nt]+b_nt[nt];
    }
  }
  long rowbase=(long)g*N_ + nodebase + w16 + quad*4;
  #pragma unroll
  for(int r=0;r<4;r++){
    unsigned short* out=hd + (rowbase+r)*64;
    #pragma unroll
    for(int nt=0;nt<4;nt++) out[nt*16+m]=f2bf(v[nt][r]);
  }
}

// ---------------- merged readouts (bf16 h) ----------------
__global__ __launch_bounds__(256) void k_readout2(const unsigned short* __restrict__ h,
    const int* __restrict__ prodi, const int* __restrict__ linei,
    const float* __restrict__ pw, const float* __restrict__ pb,
    const float* __restrict__ fw, const float* __restrict__ fb,
    float* __restrict__ outp, float* __restrict__ outf,
    float* __restrict__ pT, float* __restrict__ fT){
  int i=blockIdx.x*256+threadIdx.x;
  const int MP=B_*G_;
  const int MT=MP+B_*F_;
  if(i>=MT) return;
  bool isp=i<MP;
  int j=isp? i : i-MP;
  long n=isp? (long)prodi[j] : (long)linei[j];
  const float* wv=isp? pw:fw;
  float acc=isp? pb[0]:fb[0];
  const uint4* hp=(const uint4*)(h+n*64);
  #pragma unroll
  for(int c=0;c<8;c++){
    uint4 u=hp[c];
    unsigned int uu[4]={u.x,u.y,u.z,u.w};
    #pragma unroll
    for(int q=0;q<4;q++){
      float lo=__uint_as_float(uu[q]<<16);
      float hi=__uint_as_float(uu[q]&0xffff0000u);
      acc += lo*wv[c*8+2*q] + hi*wv[c*8+2*q+1];
    }
  }
  if(isp){ outp[j]=acc; pT[(long)(j%G_)*64 + j/G_]=acc; }
  else   { outf[j]=acc; fT[(long)(j%F_)*64 + j/F_]=acc; }
}

// ---------------- sparse md pipeline ----------------
__global__ __launch_bounds__(256) void k_md_sparsify(const float* __restrict__ gm, const float* __restrict__ lm,
    int* __restrict__ ecnt, int4* __restrict__ ent){
  const int NG4=(L_*G_)/4;
  const int NL4=(L_*F_)/4;
  int stride=gridDim.x*256;
  for(int i=blockIdx.x*256+threadIdx.x; i<NG4; i+=stride){
    float4 v=((const float4*)gm)[i];
    float c4[4]={v.x,v.y,v.z,v.w};
    #pragma unroll
    for(int q=0;q<4;q++) if(c4[q]!=0.f){
      int fi=4*i+q;
      int p=atomicAdd(ecnt,1);
      if(p<MAXE_){ int4 e; e.x=fi/G_; e.y=fi%G_; e.z=__float_as_int(c4[q]); e.w=0; ent[p]=e; }
    }
  }
  for(int i=blockIdx.x*256+threadIdx.x; i<NL4; i+=stride){
    float4 v=((const float4*)lm)[i];
    float c4[4]={v.x,v.y,v.z,v.w};
    #pragma unroll
    for(int q=0;q<4;q++) if(c4[q]!=0.f){
      int fi=4*i+q;
      int p=atomicAdd(ecnt,1);
      if(p<MAXE_){ int4 e; e.x=fi/F_; e.y=G_+fi%F_; e.z=__float_as_int(c4[q]); e.w=0; ent[p]=e; }
    }
  }
}

__global__ __launch_bounds__(256) void k_md_scatter(const int4* __restrict__ ent, const int* __restrict__ ecnt,
    const float* __restrict__ pT, const float* __restrict__ fT, float* __restrict__ mdT){
  int wv=blockIdx.x*4+(threadIdx.x>>6);
  int lane=threadIdx.x&63;
  int nE=*ecnt; if(nE>MAXE_) nE=MAXE_;
  if(wv>=nE) return;
  int4 e=ent[wv];
  float w=__int_as_float(e.z);
  float val=(e.y<G_)? pT[(long)e.y*64+lane] : fT[(long)(e.y-G_)*64+lane];
  atomicAdd(&mdT[(long)e.x*64+lane], w*val);
}

__global__ void k_md_final(const float* __restrict__ x, const int* __restrict__ loc,
    const float* __restrict__ mdT, float* __restrict__ md){
  int i=blockIdx.x*256+threadIdx.x;   // i = b*L + l
  if(i<B_*L_){
    int b=i/L_, l=i%L_;
    md[i]=x[(long)loc[i]*7]-mdT[(long)l*64+b];
  }
}

extern "C" void kernel_launch(void* const* d_in, const int* in_sizes, int n_in,
                              void* d_out, int out_size, void* d_ws, size_t ws_size,
                              hipStream_t stream){
  const float* x    =(const float*)d_in[0];
  const int*   ei   =(const int*)d_in[1];
  const int*   prodi=(const int*)d_in[2];
  const int*   linei=(const int*)d_in[3];
  const int*   loci =(const int*)d_in[4];
  const float* ew   =(const float*)d_in[5];
  const float* eb   =(const float*)d_in[6];
  const float* lng  =(const float*)d_in[7];
  const float* lnb  =(const float*)d_in[8];
  const float* wrel =(const float*)d_in[9];
  const float* brel =(const float*)d_in[10];
  const float* wroot=(const float*)d_in[11];
  const float* pw   =(const float*)d_in[12];
  const float* pb   =(const float*)d_in[13];
  const float* fw   =(const float*)d_in[14];
  const float* fb   =(const float*)d_in[15];
  const float* gm   =(const float*)d_in[16];
  const float* lm   =(const float*)d_in[17];

  char* ws=(char*)d_ws;
  unsigned short* hnA =(unsigned short*)ws;                        // NT*64 bf16
  unsigned short* hnB =hnA + (size_t)NT_*64;                       // NT*64 bf16
  unsigned short* wcat=hnB + (size_t)NT_*64;                       // 32768 bf16
  float* pT =(float*)(wcat + 32768);                               // G*B
  float* fT =pT + (size_t)G_*B_;                                   // F*B
  float* mdT=fT + (size_t)F_*B_;                                   // L*64
  int* cnt =(int*)(mdT + (size_t)L_*64);
  int* off = cnt + N_;
  int* cur = off + (N_+1);
  int* srcs= cur + N_;
  int* ecnt= srcs + EG_;
  int4* ent=(int4*)(((size_t)(ecnt+1)+15)&~(size_t)15);

  float* outp =(float*)d_out;
  float* outf =outp + (size_t)B_*G_;
  float* outmd=outf + (size_t)B_*F_;

  k_init<<<512,256,0,stream>>>(cnt,mdT,ecnt,wrel,wroot,wcat);
  k_hist<<<64,256,0,stream>>>(ei,cnt);
  k_scan<<<1,1024,0,stream>>>(cnt,off,cur,ei,srcs);
  k_md_sparsify<<<1024,256,0,stream>>>(gm,lm,ecnt,ent);
  k_enc<<<NT_/32,256,0,stream>>>(x,hnA,ew,eb,lng,lnb);
  for(int i=0;i<4;i++){
    const unsigned short* hs=(i&1)?hnB:hnA;
    unsigned short* hd=(i&1)?hnA:hnB;
    k_layer<<<B_*(N_/64),256,0,stream>>>(hs,hd,off,srcs,wcat+(size_t)i*8192,
        brel+(size_t)i*64,lng,lnb,(i<3)?1:0);
  }
  // after 4 layers (A->B->A->B->A) result is in hnA
  {
    int MT=B_*(G_+F_);
    k_readout2<<<(MT+255)/256,256,0,stream>>>(hnA,prodi,linei,pw,pb,fw,fb,outp,outf,pT,fT);
  }
  k_md_scatter<<<MAXE_/4,256,0,stream>>>(ent,ecnt,pT,fT,mdT);
  k_md_final<<<(B_*L_)/256,256,0,stream>>>(x,loci,mdT,outmd);
}

// Round 9
// 500.550 us; speedup vs baseline: 1.1480x; 1.1480x over previous
//
#include <hip/hip_runtime.h>

#define B_ 64
#define L_ 2048
#define G_ 512
#define F_ 3072
#define N_ 5632
#define NT_ 360448
#define EG_ 16384
#define E_ 1048576
#define EPS_ 1e-5f
#define CST_ 66      // cat tile stride in ushorts (33 dwords, odd -> ~2-way banks)
#define KTOT_ 3584   // md GEMM K = G + F
#define KCH_ 896     // md GEMM K-chunk (4 chunks)

typedef __attribute__((ext_vector_type(8))) short bf8v;
typedef __attribute__((ext_vector_type(4))) float f4v;

__device__ __forceinline__ unsigned short f2bf(float f){
  unsigned int u=__float_as_uint(f);
  unsigned int r=(u + 0x7fffu + ((u>>16)&1u))>>16;
  return (unsigned short)r;
}
__device__ __forceinline__ float bf2f(unsigned short h){
  return __uint_as_float(((unsigned int)h)<<16);
}

// ---------------- fused init: cnt=0, mdT=0, wcat build ----------------
__global__ void k_init(int* __restrict__ cnt, float* __restrict__ mdT,
                       const float* __restrict__ wrel, const float* __restrict__ wroot,
                       unsigned short* __restrict__ wcat){
  int i=blockIdx.x*256+threadIdx.x;      // grid covers L_*64 = 131072
  if(i<L_*64) mdT[i]=0.f;
  if(i<N_) cnt[i]=0;
  if(i<32768){
    int l=i>>13; int rest=i&8191; int n=rest>>7; int k=rest&127;
    float v=(k<64)? wrel[((long)l*64+n)*64+k] : wroot[((long)l*64+n)*64+(k-64)];
    wcat[i]=f2bf(v);
  }
}

// ---------------- CSR build (shared topology = first EG edges, graph 0) ----------------
__global__ void k_hist(const int* __restrict__ ei, int* __restrict__ cnt){
  int e=blockIdx.x*256+threadIdx.x;
  if(e<EG_) atomicAdd(&cnt[ei[E_+e]],1);
}

// shuffle-based scan
__global__ void k_scan(const int* __restrict__ cnt, int* __restrict__ off, int* __restrict__ cur){
  __shared__ int wsum[16];
  __shared__ int carry_s;
  int t=threadIdx.x, lane=t&63, wid=t>>6;
  if(t==0) carry_s=0;
  __syncthreads();
  for(int base=0;base<N_;base+=1024){
    int i=base+t;
    int v=(i<N_)?cnt[i]:0;
    int s=v;
    #pragma unroll
    for(int o=1;o<64;o<<=1){ int u=__shfl_up(s,o,64); if(lane>=o) s+=u; }
    if(lane==63) wsum[wid]=s;
    __syncthreads();
    if(t==0){
      int run=carry_s;
      #pragma unroll
      for(int q=0;q<16;q++){ int tmp=wsum[q]; wsum[q]=run; run+=tmp; }
      carry_s=run;
    }
    __syncthreads();
    int ex=wsum[wid]+s-v;
    if(i<N_){ off[i]=ex; cur[i]=ex; }
    __syncthreads();
  }
  if(t==0) off[N_]=carry_s;
}

// pack src|dst<<16 per edge (both < 5632 < 2^16)
__global__ void k_scatter(const int* __restrict__ ei, int* __restrict__ cur, int* __restrict__ srcs){
  int e=blockIdx.x*256+threadIdx.x;
  if(e<EG_){
    int d=ei[E_+e];
    int p=atomicAdd(&cur[d],1);
    srcs[p]=ei[e] | (d<<16);
  }
}

// ---------------- encoder + fused LN (produces hnA bf16 for layer 0) ----------------
__global__ __launch_bounds__(256) void k_enc(const float* __restrict__ x, unsigned short* __restrict__ hn,
    const float* __restrict__ ew, const float* __restrict__ eb,
    const float* __restrict__ lng, const float* __restrict__ lnb){
  int lane=threadIdx.x&63, wid=threadIdx.x>>6;
  int node0=blockIdx.x*32+wid*8;
  float w[7];
  #pragma unroll
  for(int k=0;k<7;k++) w[k]=ew[lane*7+k];
  float bias=eb[lane], gam=lng[lane], bet=lnb[lane];
  for(int t=0;t<8;t++){
    long n=node0+t;
    float acc=bias;
    #pragma unroll
    for(int k=0;k<7;k++) acc += x[n*7+k]*w[k];
    acc=fmaxf(acc,0.f);
    float s1=acc, s2=acc*acc;
    #pragma unroll
    for(int o=32;o>0;o>>=1){ s1+=__shfl_xor(s1,o,64); s2+=__shfl_xor(s2,o,64); }
    float mu=s1*(1.f/64.f);
    float var=s2*(1.f/64.f)-mu*mu;
    float inv=rsqrtf(var+EPS_);
    hn[n*64+lane]=f2bf((acc-mu)*inv*gam+bet);
  }
}

// ---------------- fused layer: scalar-fed gather -> MFMA -> epilogue (barrier-free) ----------------
__global__ __launch_bounds__(256,6) void k_layer(const unsigned short* __restrict__ hs,
    unsigned short* __restrict__ hd, const int* __restrict__ off, const int* __restrict__ srcs,
    const unsigned short* __restrict__ wcat, const float* __restrict__ brel,
    const float* __restrict__ lng, const float* __restrict__ lnb, int do_ln){
  __shared__ unsigned short cat[64*CST_];
  int tid=threadIdx.x;
  int w=tid>>6, lane=tid&63;
  int bid=blockIdx.x;
  const int P=N_/64;                 // 88 blocks per graph
  int r8=bid/(8*P), rem=bid%(8*P);
  int xcd=rem&7, jj=rem>>3, g=r8*8+xcd;   // one graph per XCD's L2
  int nodebase=jj*64;
  const unsigned short* hg = hs + (long)g*N_*64;
  int w16=w*16;

  // ---- phase 1: uniform edge stream + sorted-dst running flush ----
  {
    int kb=__builtin_amdgcn_readfirstlane(off[nodebase+w16]);
    int ke=__builtin_amdgcn_readfirstlane(off[nodebase+w16+16]);
    float acc=0.f;
    int dcur=w16;
#define FLUSH_(dd) while(dcur<(dd)){ cat[dcur*CST_+lane]=f2bf(acc); acc=0.f; dcur++; }
    int k=kb;
    for(; k+3<ke; k+=4){
      int u0=__builtin_amdgcn_readfirstlane(srcs[k]);
      int u1=__builtin_amdgcn_readfirstlane(srcs[k+1]);
      int u2=__builtin_amdgcn_readfirstlane(srcs[k+2]);
      int u3=__builtin_amdgcn_readfirstlane(srcs[k+3]);
      unsigned short a0=hg[(long)(u0&0xffff)*64+lane];
      unsigned short a1=hg[(long)(u1&0xffff)*64+lane];
      unsigned short a2=hg[(long)(u2&0xffff)*64+lane];
      unsigned short a3=hg[(long)(u3&0xffff)*64+lane];
      int d0=(u0>>16)-nodebase; FLUSH_(d0); acc+=bf2f(a0);
      int d1=(u1>>16)-nodebase; FLUSH_(d1); acc+=bf2f(a1);
      int d2=(u2>>16)-nodebase; FLUSH_(d2); acc+=bf2f(a2);
      int d3=(u3>>16)-nodebase; FLUSH_(d3); acc+=bf2f(a3);
    }
    for(; k<ke; k++){
      int u=__builtin_amdgcn_readfirstlane(srcs[k]);
      unsigned short a=hg[(long)(u&0xffff)*64+lane];
      int d=(u>>16)-nodebase; FLUSH_(d); acc+=bf2f(a);
    }
    FLUSH_(w16+16);
#undef FLUSH_
  }
  // no barrier: wave w writes and reads only cat rows [w16, w16+16)

  // ---- phase 2: MFMA [agg|root] @ Wcat^T, fused epilogue ----
  int m=lane&15, quad=lane>>4;
  int row=w16+m;
  const unsigned short* arow=&cat[row*CST_];
  bf8v af0=*(const bf8v*)(arow + quad*8);
  bf8v af1=*(const bf8v*)(arow + 32 + quad*8);
  const unsigned short* hrow=hg+(long)(nodebase+row)*64;
  bf8v af2=*(const bf8v*)(hrow+quad*8);
  bf8v af3=*(const bf8v*)(hrow+32+quad*8);
  f4v acc[4];
  float bias_nt[4], g_nt[4], b_nt[4];
  #pragma unroll
  for(int nt=0;nt<4;nt++){
    int c=nt*16+m;
    bias_nt[nt]=brel[c];
    g_nt[nt]=lng[c]; b_nt[nt]=lnb[c];
    acc[nt]=(f4v){0.f,0.f,0.f,0.f};
    const unsigned short* wrow=wcat + (long)c*128 + quad*8;
    bf8v b0=*(const bf8v*)(wrow);
    bf8v b1=*(const bf8v*)(wrow+32);
    bf8v b2=*(const bf8v*)(wrow+64);
    bf8v b3=*(const bf8v*)(wrow+96);
    acc[nt]=__builtin_amdgcn_mfma_f32_16x16x32_bf16(af0,b0,acc[nt],0,0,0);
    acc[nt]=__builtin_amdgcn_mfma_f32_16x16x32_bf16(af1,b1,acc[nt],0,0,0);
    acc[nt]=__builtin_amdgcn_mfma_f32_16x16x32_bf16(af2,b2,acc[nt],0,0,0);
    acc[nt]=__builtin_amdgcn_mfma_f32_16x16x32_bf16(af3,b3,acc[nt],0,0,0);
  }
  float v[4][4];
  #pragma unroll
  for(int nt=0;nt<4;nt++)
    #pragma unroll
    for(int r=0;r<4;r++)
      v[nt][r]=fmaxf(acc[nt][r]+bias_nt[nt],0.f);
  if(do_ln){
    #pragma unroll
    for(int r=0;r<4;r++){
      float rs=v[0][r]+v[1][r]+v[2][r]+v[3][r];
      float rss=v[0][r]*v[0][r]+v[1][r]*v[1][r]+v[2][r]*v[2][r]+v[3][r]*v[3][r];
      #pragma unroll
      for(int o=1;o<16;o<<=1){ rs+=__shfl_xor(rs,o,64); rss+=__shfl_xor(rss,o,64); }
      float mu=rs*(1.f/64.f);
      float var=rss*(1.f/64.f)-mu*mu;
      float inv=rsqrtf(var+EPS_);
      #pragma unroll
      for(int nt=0;nt<4;nt++) v[nt][r]=(v[nt][r]-mu)*inv*g_nt[nt]+b_nt[nt];
    }
  }
  long rowbase=(long)g*N_ + nodebase + w16 + quad*4;
  #pragma unroll
  for(int r=0;r<4;r++){
    unsigned short* out=hd + (rowbase+r)*64;
    #pragma unroll
    for(int nt=0;nt<4;nt++) out[nt*16+m]=f2bf(v[nt][r]);
  }
}

// ---------------- merged readouts; also emit double-bf16 pf rows for md GEMM ----------------
__global__ __launch_bounds__(256) void k_readout2(const unsigned short* __restrict__ h,
    const int* __restrict__ prodi, const int* __restrict__ linei,
    const float* __restrict__ pw, const float* __restrict__ pb,
    const float* __restrict__ fw, const float* __restrict__ fb,
    float* __restrict__ outp, float* __restrict__ outf,
    unsigned short* __restrict__ pfhi, unsigned short* __restrict__ pflo){
  int i=blockIdx.x*256+threadIdx.x;
  const int MP=B_*G_;
  const int MT=MP+B_*F_;
  if(i>=MT) return;
  bool isp=i<MP;
  int j=isp? i : i-MP;
  long n=isp? (long)prodi[j] : (long)linei[j];
  const float* wv=isp? pw:fw;
  float acc=isp? pb[0]:fb[0];
  const uint4* hp=(const uint4*)(h+n*64);
  #pragma unroll
  for(int c=0;c<8;c++){
    uint4 u=hp[c];
    unsigned int uu[4]={u.x,u.y,u.z,u.w};
    #pragma unroll
    for(int q=0;q<4;q++){
      float lo=__uint_as_float(uu[q]<<16);
      float hi=__uint_as_float(uu[q]&0xffff0000u);
      acc += lo*wv[c*8+2*q] + hi*wv[c*8+2*q+1];
    }
  }
  int b,kcol;
  if(isp){ outp[j]=acc; b=j/G_; kcol=j%G_; }
  else   { outf[j]=acc; b=j/F_; kcol=G_+j%F_; }
  unsigned short hi=f2bf(acc);
  pfhi[(long)b*KTOT_+kcol]=hi;
  pflo[(long)b*KTOT_+kcol]=f2bf(acc-bf2f(hi));
}

// ---------------- md dense GEMM: mdT[l][b] += sum_k mask[l][k]*pf[b][k] ----------------
// 128 blocks = 32 loc-tiles x 4 K-chunks; double-bf16 B for ~fp32 accuracy.
__global__ __launch_bounds__(256) void k_md_gemm(const float* __restrict__ gm, const float* __restrict__ lm,
    const unsigned short* __restrict__ pfhi, const unsigned short* __restrict__ pflo,
    float* __restrict__ mdT){
  int tid=threadIdx.x;
  int w=tid>>6, lane=tid&63;
  int m=lane&15, quad=lane>>4;
  int lb=blockIdx.x>>2, kc=blockIdx.x&3;
  int l=lb*64 + w*16 + m;              // A (mask) row for this lane
  f4v acc[4];
  #pragma unroll
  for(int nt=0;nt<4;nt++) acc[nt]=(f4v){0.f,0.f,0.f,0.f};
  int kk0=kc*KCH_;
  for(int s=0;s<KCH_/32;s++){
    int kk=kk0+s*32;
    const float* ap = (kk<G_)? gm + (long)l*G_ + kk : lm + (long)l*F_ + (kk-G_);
    float4 a0=*(const float4*)(ap+quad*8);
    float4 a1=*(const float4*)(ap+quad*8+4);
    bf8v af;
    af[0]=(short)f2bf(a0.x); af[1]=(short)f2bf(a0.y);
    af[2]=(short)f2bf(a0.z); af[3]=(short)f2bf(a0.w);
    af[4]=(short)f2bf(a1.x); af[5]=(short)f2bf(a1.y);
    af[6]=(short)f2bf(a1.z); af[7]=(short)f2bf(a1.w);
    #pragma unroll
    for(int nt=0;nt<4;nt++){
      int b=nt*16+m;
      const unsigned short* bp=pfhi + (long)b*KTOT_ + kk + quad*8;
      const unsigned short* lp=pflo + (long)b*KTOT_ + kk + quad*8;
      bf8v bh=*(const bf8v*)bp;
      bf8v bl=*(const bf8v*)lp;
      acc[nt]=__builtin_amdgcn_mfma_f32_16x16x32_bf16(af,bh,acc[nt],0,0,0);
      acc[nt]=__builtin_amdgcn_mfma_f32_16x16x32_bf16(af,bl,acc[nt],0,0,0);
    }
  }
  int lrow=lb*64 + w*16 + quad*4;
  #pragma unroll
  for(int r=0;r<4;r++)
    #pragma unroll
    for(int nt=0;nt<4;nt++)
      atomicAdd(&mdT[(long)(lrow+r)*64 + nt*16 + m], acc[nt][r]);
}

__global__ void k_md_final(const float* __restrict__ x, const int* __restrict__ loc,
    const float* __restrict__ mdT, float* __restrict__ md){
  int i=blockIdx.x*256+threadIdx.x;   // i = b*L + l
  if(i<B_*L_){
    int b=i/L_, l=i%L_;
    md[i]=x[(long)loc[i]*7]-mdT[(long)l*64+b];
  }
}

extern "C" void kernel_launch(void* const* d_in, const int* in_sizes, int n_in,
                              void* d_out, int out_size, void* d_ws, size_t ws_size,
                              hipStream_t stream){
  const float* x    =(const float*)d_in[0];
  const int*   ei   =(const int*)d_in[1];
  const int*   prodi=(const int*)d_in[2];
  const int*   linei=(const int*)d_in[3];
  const int*   loci =(const int*)d_in[4];
  const float* ew   =(const float*)d_in[5];
  const float* eb   =(const float*)d_in[6];
  const float* lng  =(const float*)d_in[7];
  const float* lnb  =(const float*)d_in[8];
  const float* wrel =(const float*)d_in[9];
  const float* brel =(const float*)d_in[10];
  const float* wroot=(const float*)d_in[11];
  const float* pw   =(const float*)d_in[12];
  const float* pb   =(const float*)d_in[13];
  const float* fw   =(const float*)d_in[14];
  const float* fb   =(const float*)d_in[15];
  const float* gm   =(const float*)d_in[16];
  const float* lm   =(const float*)d_in[17];

  char* ws=(char*)d_ws;
  unsigned short* hnA =(unsigned short*)ws;                        // NT*64 bf16
  unsigned short* hnB =hnA + (size_t)NT_*64;                       // NT*64 bf16
  unsigned short* wcat=hnB + (size_t)NT_*64;                       // 32768 bf16
  unsigned short* pfhi=wcat + 32768;                               // B*KTOT bf16
  unsigned short* pflo=pfhi + (size_t)B_*KTOT_;                    // B*KTOT bf16
  float* mdT=(float*)(pflo + (size_t)B_*KTOT_);                    // L*64 f32
  int* cnt =(int*)(mdT + (size_t)L_*64);
  int* off = cnt + N_;
  int* cur = off + (N_+1);
  int* srcs= cur + N_;

  float* outp =(float*)d_out;
  float* outf =outp + (size_t)B_*G_;
  float* outmd=outf + (size_t)B_*F_;

  k_init<<<512,256,0,stream>>>(cnt,mdT,wrel,wroot,wcat);
  k_hist<<<64,256,0,stream>>>(ei,cnt);
  k_scan<<<1,1024,0,stream>>>(cnt,off,cur);
  k_scatter<<<64,256,0,stream>>>(ei,cur,srcs);
  k_enc<<<NT_/32,256,0,stream>>>(x,hnA,ew,eb,lng,lnb);
  for(int i=0;i<4;i++){
    const unsigned short* hs=(i&1)?hnB:hnA;
    unsigned short* hd=(i&1)?hnA:hnB;
    k_layer<<<B_*(N_/64),256,0,stream>>>(hs,hd,off,srcs,wcat+(size_t)i*8192,
        brel+(size_t)i*64,lng,lnb,(i<3)?1:0);
  }
  // after 4 layers (A->B->A->B->A) result is in hnA
  {
    int MT=B_*(G_+F_);
    k_readout2<<<(MT+255)/256,256,0,stream>>>(hnA,prodi,linei,pw,pb,fw,fb,outp,outf,pfhi,pflo);
  }
  k_md_gemm<<<128,256,0,stream>>>(gm,lm,pfhi,pflo,mdT);
  k_md_final<<<(B_*L_)/256,256,0,stream>>>(x,loci,mdT,outmd);
}